// Round 7
// baseline (373.711 us; speedup 1.0000x reference)
//
#include <hip/hip_runtime.h>
#include <hip/hip_fp16.h>
#include <math.h>

#define NN 25000
#define NE 400000
#define HID 64
#define F_IN 256
#define N_CLASS 32
#define MAXL 4          // x_all stores up to 4 layer slices
#define KVS 3           // K/V layer slots
#define WPAD 264        // f16 row stride of W^T in LDS (256 + 8 pad -> 4-bank rotate)
#define SCAN_NB 98      // ceil(NN/256)

typedef _Float16 f16;
typedef _Float16 f16x2 __attribute__((ext_vector_type(2)));
typedef _Float16 f16x8 __attribute__((ext_vector_type(8)));
typedef float f32x4 __attribute__((ext_vector_type(4)));

union F16x8 {
    f16x8 v;
    f16x2 h[4];
    __half2 hh[4];
};

__device__ __forceinline__ float dot2(f16x2 a, f16x2 b, float c) {
#if __has_builtin(__builtin_amdgcn_fdot2)
    return __builtin_amdgcn_fdot2(a, b, c, false);
#else
    return c + (float)a[0] * (float)b[0] + (float)a[1] * (float)b[1];
#endif
}

// ---------- degree ----------
__global__ void deg_kernel(const int* __restrict__ col, int* __restrict__ deg, int E) {
    int e = blockIdx.x * blockDim.x + threadIdx.x;
    if (e < E) atomicAdd(&deg[col[e]], 1);
}

// ---------- device-wide exclusive scan, 3 phases ----------
__global__ void scanA_kernel(const int* __restrict__ deg, int* __restrict__ bsum, int n) {
    int t = threadIdx.x;
    int i = blockIdx.x * 256 + t;
    int v = (i < n) ? deg[i] : 0;
    #pragma unroll
    for (int off = 1; off < 64; off <<= 1) v += __shfl_xor(v, off);
    __shared__ int wsum[4];
    if ((t & 63) == 0) wsum[t >> 6] = v;
    __syncthreads();
    if (t == 0) bsum[blockIdx.x] = wsum[0] + wsum[1] + wsum[2] + wsum[3];
}

__global__ void scanB_kernel(int* __restrict__ bsum, int nb) {
    __shared__ int s[128];
    int t = threadIdx.x;
    int v = (t < nb) ? bsum[t] : 0;
    s[t] = v;
    __syncthreads();
    for (int off = 1; off < 128; off <<= 1) {
        int u = (t >= off) ? s[t - off] : 0;
        __syncthreads();
        s[t] += u;
        __syncthreads();
    }
    if (t < nb) bsum[t] = s[t] - v;   // exclusive
}

__global__ void scanC_kernel(const int* __restrict__ deg, const int* __restrict__ bsum,
                             int* __restrict__ rowptr, int* __restrict__ cursor,
                             float* __restrict__ dis, int n) {
    int t = threadIdx.x;
    int i = blockIdx.x * 256 + t;
    int lane = t & 63, w = t >> 6;
    int v = (i < n) ? deg[i] : 0;
    int x = v;   // inclusive wave scan
    #pragma unroll
    for (int off = 1; off < 64; off <<= 1) {
        int u = __shfl_up(x, off);
        if (lane >= off) x += u;
    }
    __shared__ int wsum[4];
    if (lane == 63) wsum[w] = x;
    __syncthreads();
    int base = bsum[blockIdx.x];
    for (int ww = 0; ww < w; ++ww) base += wsum[ww];
    if (i < n) {
        int excl = base + x - v;
        rowptr[i] = excl;
        cursor[i] = excl;
        dis[i] = rsqrtf((float)(v + 1));   // +1 self loop
    }
}

// ---------- scatter edges into CSR (grouped by destination col) ----------
__global__ void scatter_kernel(const int* __restrict__ row, const int* __restrict__ col,
                               int* __restrict__ cursor, int* __restrict__ csr_src, int E) {
    int e = blockIdx.x * blockDim.x + threadIdx.x;
    if (e >= E) return;
    int c = col[e];
    int p = atomicAdd(&cursor[c], 1);
    csr_src[p] = row[e];
}

// ---------- W1 -> fp16 transposed: wt[n][k] = (f16) w[k*64+n] ----------
__global__ void wprep_kernel(const float* __restrict__ w, f16* __restrict__ wt) {
    int e = blockIdx.x * blockDim.x + threadIdx.x;  // 16384 elements
    int k = e >> 6, nn = e & 63;
    wt[nn * F_IN + k] = (f16)w[e];
}

// ---------- lin1 via MFMA: h = relu(x @ W1 + b1) -> x_all layer 0 ----------
__global__ void __launch_bounds__(256) lin1_mfma_kernel(
        const float* __restrict__ x, const f16x8* __restrict__ wt,
        const float* __restrict__ b, float* __restrict__ x_all, int n) {
    __shared__ f16 wlds[64 * WPAD];
    int t = threadIdx.x;
    #pragma unroll
    for (int j = 0; j < 8; ++j) {                 // stage all 2048 f16x8 units (32 KB)
        int idx = t + j * 256;
        int e = idx * 8;
        int nr = e >> 8, k0 = e & 255;
        *(f16x8*)&wlds[nr * WPAD + k0] = wt[idx];
    }
    __syncthreads();
    int wave = t >> 6, lane = t & 63;
    int m = lane & 15, quad = lane >> 4;
    int rowA = blockIdx.x * 64 + wave * 16 + m;
    int rA = min(rowA, n - 1);                    // clamp; masked at store
    const float* xp = x + (size_t)rA * F_IN + quad * 8;
    f32x4 acc[4] = {};
    for (int kk = 0; kk < F_IN; kk += 32) {
        float4 x0 = *(const float4*)(xp + kk);
        float4 x1 = *(const float4*)(xp + kk + 4);
        f16x8 a;
        a[0] = (f16)x0.x; a[1] = (f16)x0.y; a[2] = (f16)x0.z; a[3] = (f16)x0.w;
        a[4] = (f16)x1.x; a[5] = (f16)x1.y; a[6] = (f16)x1.z; a[7] = (f16)x1.w;
        #pragma unroll
        for (int nt = 0; nt < 4; ++nt) {
            f16x8 bf = *(const f16x8*)&wlds[(nt * 16 + m) * WPAD + kk + quad * 8];
            acc[nt] = __builtin_amdgcn_mfma_f32_16x16x32_f16(a, bf, acc[nt], 0, 0, 0);
        }
    }
    int rowC = blockIdx.x * 64 + wave * 16 + quad * 4;
    #pragma unroll
    for (int nt = 0; nt < 4; ++nt) {
        int col = nt * 16 + m;
        float bias = b[col];
        #pragma unroll
        for (int r = 0; r < 4; ++r) {
            int row = rowC + r;
            if (row < n)
                x_all[(size_t)row * (MAXL * HID) + col] = fmaxf(acc[nt][r] + bias, 0.f);
        }
    }
}

// ---------- layer-0 q/k/v grouped-linear transform (fp16-packed outputs) ----------
// out[d] = b[d] + sum_i x[g*8+i] * w[g*64 + i*8 + o], g=d>>3, o=d&7
__global__ void transform0_kernel(const float* __restrict__ x_all,
                                  const float* __restrict__ wq, const float* __restrict__ bq,
                                  const float* __restrict__ wk, const float* __restrict__ bk,
                                  const float* __restrict__ wv, const float* __restrict__ bv,
                                  f16x2* __restrict__ Q2, f16x2* __restrict__ KV, int n) {
    int t = blockIdx.x * blockDim.x + threadIdx.x;
    int node = t >> 5, u = t & 31;
    if (node >= n) return;
    int g = u >> 2;
    int o0 = (u & 3) * 2;
    const float* xg = x_all + (size_t)node * (MAXL * HID) + g * 8;  // slice 0

    float a0 = bq[g * 8 + o0], a1 = bq[g * 8 + o0 + 1];
    float k0 = bk[g * 8 + o0], k1 = bk[g * 8 + o0 + 1];
    float v0 = bv[g * 8 + o0], v1 = bv[g * 8 + o0 + 1];
    const float* wgq = wq + g * 64;
    const float* wgk = wk + g * 64;
    const float* wgv = wv + g * 64;
    #pragma unroll
    for (int i = 0; i < 8; ++i) {
        float xv = xg[i];
        a0 = fmaf(xv, wgq[i * 8 + o0], a0);
        a1 = fmaf(xv, wgq[i * 8 + o0 + 1], a1);
        k0 = fmaf(xv, wgk[i * 8 + o0], k0);
        k1 = fmaf(xv, wgk[i * 8 + o0 + 1], k1);
        v0 = fmaf(xv, wgv[i * 8 + o0], v0);
        v1 = fmaf(xv, wgv[i * 8 + o0 + 1], v1);
    }
    f16x2 qh; qh[0] = (f16)a0; qh[1] = (f16)a1;
    f16x2 kh; kh[0] = (f16)k0; kh[1] = (f16)k1;
    f16x2 vh; vh[0] = (f16)v0; vh[1] = (f16)v1;
    Q2[(size_t)node * 32 + u] = qh;
    size_t base = (size_t)node * (KVS * 2);      // slice 0
    KV[(base + 0) * 32 + u] = kh;
    KV[(base + 1) * 32 + u] = vh;
}

// ---------- gather + attend (+ fused next-layer transform epilogue) ----------
// One wave64 per destination node. lane = slot*8 + head(u); each lane holds its
// head's 8 dims in-register. 16 edges in flight per iteration (2 per slot).
// EPI: after the slot butterfly every lane has the full new slice for its head;
// slots 0..L compute next-layer K/V for slice 'slot' (slot L uses the in-register
// new slice), slot L+1 computes next-layer Q. Double-buffered Q/KV (r vs w).
template <int L, bool EPI>
__global__ void gather_kernel(const int* __restrict__ rowptr, const int* __restrict__ deg,
                              const int* __restrict__ csr_src, const float* __restrict__ dis,
                              const f16x8* __restrict__ Q8r, const f16x8* __restrict__ KV8r,
                              f16x8* __restrict__ Q8w, f16x8* __restrict__ KV8w,
                              const float* __restrict__ wqn, const float* __restrict__ bqn,
                              const float* __restrict__ wkn, const float* __restrict__ bkn,
                              const float* __restrict__ wvn, const float* __restrict__ bvn,
                              float* __restrict__ x_all, int n) {
    int wave = (int)((blockIdx.x * (size_t)blockDim.x + threadIdx.x) >> 6);
    int lane = threadIdx.x & 63;
    if (wave >= n) return;
    int c = wave;
    int u = lane & 7;         // head
    int slot = lane >> 3;     // edge slot
    F16x8 q; q.v = Q8r[(size_t)c * 8 + u];
    float nc = dis[c];
    int beg = rowptr[c];
    int dc = deg[c] + 1;      // + self loop
    float acc[8];
    #pragma unroll
    for (int i = 0; i < 8; ++i) acc[i] = 0.f;

    for (int j = 0; j < dc; j += 16) {
        int jj0 = j + slot;
        int jj1 = j + slot + 8;
        bool va0 = jj0 < dc, va1 = jj1 < dc;
        int r0 = c, r1 = c;
        if (va0 && jj0 > 0) r0 = csr_src[beg + jj0 - 1];
        if (va1)            r1 = csr_src[beg + jj1 - 1];
        float nrm0 = va0 ? nc * dis[r0] : 0.f;
        float nrm1 = va1 ? nc * dis[r1] : 0.f;

        F16x8 kk0[L], vv0[L], kk1[L], vv1[L];
        size_t rb0 = (size_t)r0 * (KVS * 2 * 8);
        size_t rb1 = (size_t)r1 * (KVS * 2 * 8);
        #pragma unroll
        for (int ll = 0; ll < L; ++ll) {
            kk0[ll].v = KV8r[rb0 + ll * 16 + u];
            vv0[ll].v = KV8r[rb0 + ll * 16 + 8 + u];
            kk1[ll].v = KV8r[rb1 + ll * 16 + u];
            vv1[ll].v = KV8r[rb1 + ll * 16 + 8 + u];
        }
        float s0[L], s1[L];
        #pragma unroll
        for (int ll = 0; ll < L; ++ll) {
            float p0 = 0.f, p1 = 0.f;
            #pragma unroll
            for (int i2 = 0; i2 < 4; ++i2) {
                p0 = dot2(q.h[i2], kk0[ll].h[i2], p0);
                p1 = dot2(q.h[i2], kk1[ll].h[i2], p1);
            }
            s0[ll] = p0 * 0.35355339059327373f;   // 1/sqrt(8)
            s1[ll] = p1 * 0.35355339059327373f;
        }
        float m0 = s0[0], m1 = s1[0];
        #pragma unroll
        for (int ll = 1; ll < L; ++ll) { m0 = fmaxf(m0, s0[ll]); m1 = fmaxf(m1, s1[ll]); }
        float sum0 = 0.f, sum1 = 0.f;
        #pragma unroll
        for (int ll = 0; ll < L; ++ll) {
            s0[ll] = __expf(s0[ll] - m0); sum0 += s0[ll];
            s1[ll] = __expf(s1[ll] - m1); sum1 += s1[ll];
        }
        float inv0 = nrm0 / sum0;
        float inv1 = nrm1 / sum1;

        __half2 ha[4];
        #pragma unroll
        for (int i2 = 0; i2 < 4; ++i2) ha[i2] = __float2half2_rn(0.f);
        #pragma unroll
        for (int ll = 0; ll < L; ++ll) {
            __half2 p0 = __float2half2_rn(s0[ll] * inv0);
            __half2 p1 = __float2half2_rn(s1[ll] * inv1);
            #pragma unroll
            for (int i2 = 0; i2 < 4; ++i2) {
                ha[i2] = __hfma2(p0, vv0[ll].hh[i2], ha[i2]);
                ha[i2] = __hfma2(p1, vv1[ll].hh[i2], ha[i2]);
            }
        }
        #pragma unroll
        for (int i2 = 0; i2 < 4; ++i2) {
            float2 f = __half22float2(ha[i2]);
            acc[i2 * 2]     += f.x;
            acc[i2 * 2 + 1] += f.y;
        }
    }
    // butterfly over the 8 edge slots: every lane ends with the full sums
    #pragma unroll
    for (int off = 8; off < 64; off <<= 1) {
        #pragma unroll
        for (int i = 0; i < 8; ++i) acc[i] += __shfl_xor(acc[i], off);
    }
    float xn[8];
    #pragma unroll
    for (int i = 0; i < 8; ++i) xn[i] = fmaxf(acc[i], 0.f);
    if (slot == 0) {
        float4* dst = (float4*)(x_all + ((size_t)c * MAXL + L) * HID + u * 8);
        dst[0] = make_float4(xn[0], xn[1], xn[2], xn[3]);
        dst[1] = make_float4(xn[4], xn[5], xn[6], xn[7]);
    }
    if constexpr (EPI) {
        // next layer has slices 0..L; Q from slice L.
        if (slot <= L + 1) {
            bool isQ = (slot == L + 1);
            int s = isQ ? L : slot;
            float xs[8];
            if (s == L) {
                #pragma unroll
                for (int i = 0; i < 8; ++i) xs[i] = xn[i];
            } else {
                const float* xo = x_all + ((size_t)c * MAXL + s) * HID + u * 8;
                float4 a0 = *(const float4*)xo;
                float4 a1 = *(const float4*)(xo + 4);
                xs[0] = a0.x; xs[1] = a0.y; xs[2] = a0.z; xs[3] = a0.w;
                xs[4] = a1.x; xs[5] = a1.y; xs[6] = a1.z; xs[7] = a1.w;
            }
            if (isQ) {
                float o[8];
                #pragma unroll
                for (int oo = 0; oo < 8; ++oo) o[oo] = bqn[u * 8 + oo];
                const float* wg = wqn + u * 64;
                #pragma unroll
                for (int i = 0; i < 8; ++i)
                    #pragma unroll
                    for (int oo = 0; oo < 8; ++oo) o[oo] = fmaf(xs[i], wg[i * 8 + oo], o[oo]);
                F16x8 pk;
                #pragma unroll
                for (int oo = 0; oo < 8; ++oo) pk.v[oo] = (f16)o[oo];
                Q8w[(size_t)c * 8 + u] = pk.v;
            } else {
                float ok[8], ov[8];
                #pragma unroll
                for (int oo = 0; oo < 8; ++oo) { ok[oo] = bkn[u * 8 + oo]; ov[oo] = bvn[u * 8 + oo]; }
                const float* wgk = wkn + u * 64;
                const float* wgv = wvn + u * 64;
                #pragma unroll
                for (int i = 0; i < 8; ++i) {
                    float xv = xs[i];
                    #pragma unroll
                    for (int oo = 0; oo < 8; ++oo) {
                        ok[oo] = fmaf(xv, wgk[i * 8 + oo], ok[oo]);
                        ov[oo] = fmaf(xv, wgv[i * 8 + oo], ov[oo]);
                    }
                }
                F16x8 pk, pv;
                #pragma unroll
                for (int oo = 0; oo < 8; ++oo) { pk.v[oo] = (f16)ok[oo]; pv.v[oo] = (f16)ov[oo]; }
                size_t base = (size_t)c * (KVS * 2 * 8) + s * 16;
                KV8w[base + u]     = pk.v;
                KV8w[base + 8 + u] = pv.v;
            }
        }
    }
}

// ---------- final: logits = x_all[:,3] @ W2 + b2; log_softmax over 32 classes ----------
__global__ void final_kernel(const float* __restrict__ x_all, const float* __restrict__ w2,
                             const float* __restrict__ b2, float* __restrict__ out, int n) {
    int t = blockIdx.x * blockDim.x + threadIdx.x;
    int node = t >> 5;
    int o = t & 31;
    if (node >= n) return;
    const float* xr = x_all + (size_t)node * (MAXL * HID) + 3 * HID;
    float logit = b2[o];
    #pragma unroll
    for (int d = 0; d < HID; ++d) logit = fmaf(xr[d], w2[d * N_CLASS + o], logit);
    float m = logit;
    for (int off = 16; off; off >>= 1) m = fmaxf(m, __shfl_xor(m, off, 32));
    float e = expf(logit - m);
    float sum = e;
    for (int off = 16; off; off >>= 1) sum += __shfl_xor(sum, off, 32);
    out[(size_t)node * N_CLASS + o] = (logit - m) - logf(sum);
}

extern "C" void kernel_launch(void* const* d_in, const int* in_sizes, int n_in,
                              void* d_out, int out_size, void* d_ws, size_t ws_size,
                              hipStream_t stream) {
    const float* x      = (const float*)d_in[0];
    const int*   eidx   = (const int*)d_in[1];     // (2, E)
    const float* lin1_w = (const float*)d_in[2];
    const float* lin1_b = (const float*)d_in[3];
    const float* wq     = (const float*)d_in[4];   // (3, 8, 8, 8)
    const float* bq     = (const float*)d_in[5];   // (3, 64)
    const float* wk     = (const float*)d_in[6];
    const float* bk     = (const float*)d_in[7];
    const float* wv     = (const float*)d_in[8];
    const float* bv     = (const float*)d_in[9];
    const float* lin2_w = (const float*)d_in[10];  // (64, 32)
    const float* lin2_b = (const float*)d_in[11];
    float* out = (float*)d_out;

    const int n  = NN;
    const int E  = NE;
    const int* row = eidx;
    const int* col = eidx + E;

    // workspace layout (16B-aligned where vector-accessed)
    char* ws = (char*)d_ws;
    float*  x_all  = (float*)ws;   ws += (size_t)NN * MAXL * HID * 4;        // 25.6 MB
    f16*    Qa     = (f16*)ws;     ws += (size_t)NN * HID * 2;               // 3.2 MB
    f16*    KVa    = (f16*)ws;     ws += (size_t)NN * KVS * 2 * HID * 2;     // 19.2 MB
    f16*    Qb     = (f16*)ws;     ws += (size_t)NN * HID * 2;               // 3.2 MB
    f16*    KVb    = (f16*)ws;     ws += (size_t)NN * KVS * 2 * HID * 2;     // 19.2 MB
    float*  dis    = (float*)ws;   ws += (size_t)NN * 4;
    int*    deg    = (int*)ws;     ws += (size_t)NN * 4;
    int*    rowptr = (int*)ws;     ws += (size_t)NN * 4;
    int*    cursor = (int*)ws;     ws += (size_t)NN * 4;
    int*    csr    = (int*)ws;     ws += (size_t)NE * 4;                     // 1.6 MB
    f16*    wt16   = (f16*)ws;     ws += (size_t)HID * F_IN * 2;             // 32 KB
    int*    bsum   = (int*)ws;     ws += 128 * 4;

    // 1. degree + norm + CSR build (+ W1 fp16 transpose)
    hipMemsetAsync(deg, 0, (size_t)NN * 4, stream);
    deg_kernel<<<(E + 255) / 256, 256, 0, stream>>>(col, deg, E);
    scanA_kernel<<<SCAN_NB, 256, 0, stream>>>(deg, bsum, n);
    scanB_kernel<<<1, 128, 0, stream>>>(bsum, SCAN_NB);
    scanC_kernel<<<SCAN_NB, 256, 0, stream>>>(deg, bsum, rowptr, cursor, dis, n);
    scatter_kernel<<<(E + 255) / 256, 256, 0, stream>>>(row, col, cursor, csr, E);
    wprep_kernel<<<(HID * F_IN + 255) / 256, 256, 0, stream>>>(lin1_w, wt16);

    // 2. lin1 (MFMA) -> x_all layer 0
    lin1_mfma_kernel<<<(n + 63) / 64, 256, 0, stream>>>(x, (const f16x8*)wt16, lin1_b, x_all, n);

    // 3. layer-0 transform, then three gathers with fused next-layer transforms
    transform0_kernel<<<(n * 32 + 255) / 256, 256, 0, stream>>>(
        x_all, wq, bq, wk, bk, wv, bv, (f16x2*)Qa, (f16x2*)KVa, n);

    int blocks = (n + 3) / 4;   // 4 nodes (waves) per 256-thread block
    gather_kernel<1, true><<<blocks, 256, 0, stream>>>(
        rowptr, deg, csr, dis, (const f16x8*)Qa, (const f16x8*)KVa,
        (f16x8*)Qb, (f16x8*)KVb,
        wq + 512, bq + 64, wk + 512, bk + 64, wv + 512, bv + 64, x_all, n);
    gather_kernel<2, true><<<blocks, 256, 0, stream>>>(
        rowptr, deg, csr, dis, (const f16x8*)Qb, (const f16x8*)KVb,
        (f16x8*)Qa, (f16x8*)KVa,
        wq + 1024, bq + 128, wk + 1024, bk + 128, wv + 1024, bv + 128, x_all, n);
    gather_kernel<3, false><<<blocks, 256, 0, stream>>>(
        rowptr, deg, csr, dis, (const f16x8*)Qa, (const f16x8*)KVa,
        (f16x8*)Qb, (f16x8*)KVb,   // unused (EPI=false)
        wq, bq, wk, bk, wv, bv, x_all, n);

    // 4. classifier + log_softmax
    final_kernel<<<(n * N_CLASS + 255) / 256, 256, 0, stream>>>(x_all, lin2_w, lin2_b, out, n);
}

// Round 8
// 297.762 us; speedup vs baseline: 1.2551x; 1.2551x over previous
//
#include <hip/hip_runtime.h>
#include <hip/hip_fp16.h>
#include <math.h>

#define NN 25000
#define NE 400000
#define HID 64
#define F_IN 256
#define N_CLASS 32
#define MAXL 4          // x_all stores up to 4 layer slices
#define KVS 3           // K/V layer slots
#define WPAD 264        // f16 row stride of W^T in LDS (256 + 8 pad -> 4-bank rotate)
#define SCAN_NB 98      // ceil(NN/256)

typedef _Float16 f16;
typedef _Float16 f16x2 __attribute__((ext_vector_type(2)));
typedef _Float16 f16x8 __attribute__((ext_vector_type(8)));
typedef float f32x4 __attribute__((ext_vector_type(4)));

union F16x8 {
    f16x8 v;
    f16x2 h[4];
    __half2 hh[4];
};

__device__ __forceinline__ float dot2(f16x2 a, f16x2 b, float c) {
#if __has_builtin(__builtin_amdgcn_fdot2)
    return __builtin_amdgcn_fdot2(a, b, c, false);
#else
    return c + (float)a[0] * (float)b[0] + (float)a[1] * (float)b[1];
#endif
}

// ---------- degree ----------
__global__ void deg_kernel(const int* __restrict__ col, int* __restrict__ deg, int E) {
    int e = blockIdx.x * blockDim.x + threadIdx.x;
    if (e < E) atomicAdd(&deg[col[e]], 1);
}

// ---------- device-wide exclusive scan, 3 phases ----------
__global__ void scanA_kernel(const int* __restrict__ deg, int* __restrict__ bsum, int n) {
    int t = threadIdx.x;
    int i = blockIdx.x * 256 + t;
    int v = (i < n) ? deg[i] : 0;
    #pragma unroll
    for (int off = 1; off < 64; off <<= 1) v += __shfl_xor(v, off);
    __shared__ int wsum[4];
    if ((t & 63) == 0) wsum[t >> 6] = v;
    __syncthreads();
    if (t == 0) bsum[blockIdx.x] = wsum[0] + wsum[1] + wsum[2] + wsum[3];
}

__global__ void scanB_kernel(int* __restrict__ bsum, int nb) {
    __shared__ int s[128];
    int t = threadIdx.x;
    int v = (t < nb) ? bsum[t] : 0;
    s[t] = v;
    __syncthreads();
    for (int off = 1; off < 128; off <<= 1) {
        int u = (t >= off) ? s[t - off] : 0;
        __syncthreads();
        s[t] += u;
        __syncthreads();
    }
    if (t < nb) bsum[t] = s[t] - v;   // exclusive
}

__global__ void scanC_kernel(const int* __restrict__ deg, const int* __restrict__ bsum,
                             int* __restrict__ rowptr, int* __restrict__ cursor,
                             float* __restrict__ dis, int n) {
    int t = threadIdx.x;
    int i = blockIdx.x * 256 + t;
    int lane = t & 63, w = t >> 6;
    int v = (i < n) ? deg[i] : 0;
    int x = v;   // inclusive wave scan
    #pragma unroll
    for (int off = 1; off < 64; off <<= 1) {
        int u = __shfl_up(x, off);
        if (lane >= off) x += u;
    }
    __shared__ int wsum[4];
    if (lane == 63) wsum[w] = x;
    __syncthreads();
    int base = bsum[blockIdx.x];
    for (int ww = 0; ww < w; ++ww) base += wsum[ww];
    if (i < n) {
        int excl = base + x - v;
        rowptr[i] = excl;
        cursor[i] = excl;
        dis[i] = rsqrtf((float)(v + 1));   // +1 self loop
    }
}

// ---------- scatter edges into CSR (grouped by destination col) ----------
__global__ void scatter_kernel(const int* __restrict__ row, const int* __restrict__ col,
                               int* __restrict__ cursor, int* __restrict__ csr_src, int E) {
    int e = blockIdx.x * blockDim.x + threadIdx.x;
    if (e >= E) return;
    int c = col[e];
    int p = atomicAdd(&cursor[c], 1);
    csr_src[p] = row[e];
}

// ---------- W1 -> fp16 transposed: wt[n][k] = (f16) w[k*64+n] ----------
__global__ void wprep_kernel(const float* __restrict__ w, f16* __restrict__ wt) {
    int e = blockIdx.x * blockDim.x + threadIdx.x;  // 16384 elements
    int k = e >> 6, nn = e & 63;
    wt[nn * F_IN + k] = (f16)w[e];
}

// ---------- lin1 via MFMA: h = relu(x @ W1 + b1) -> x_all layer 0 ----------
__global__ void __launch_bounds__(256) lin1_mfma_kernel(
        const float* __restrict__ x, const f16x8* __restrict__ wt,
        const float* __restrict__ b, float* __restrict__ x_all, int n) {
    __shared__ f16 wlds[64 * WPAD];
    int t = threadIdx.x;
    #pragma unroll
    for (int j = 0; j < 8; ++j) {                 // stage all 2048 f16x8 units (32 KB)
        int idx = t + j * 256;
        int e = idx * 8;
        int nr = e >> 8, k0 = e & 255;
        *(f16x8*)&wlds[nr * WPAD + k0] = wt[idx];
    }
    __syncthreads();
    int wave = t >> 6, lane = t & 63;
    int m = lane & 15, quad = lane >> 4;
    int rowA = blockIdx.x * 64 + wave * 16 + m;
    int rA = min(rowA, n - 1);                    // clamp; masked at store
    const float* xp = x + (size_t)rA * F_IN + quad * 8;
    f32x4 acc[4] = {};
    for (int kk = 0; kk < F_IN; kk += 32) {
        float4 x0 = *(const float4*)(xp + kk);
        float4 x1 = *(const float4*)(xp + kk + 4);
        f16x8 a;
        a[0] = (f16)x0.x; a[1] = (f16)x0.y; a[2] = (f16)x0.z; a[3] = (f16)x0.w;
        a[4] = (f16)x1.x; a[5] = (f16)x1.y; a[6] = (f16)x1.z; a[7] = (f16)x1.w;
        #pragma unroll
        for (int nt = 0; nt < 4; ++nt) {
            f16x8 bf = *(const f16x8*)&wlds[(nt * 16 + m) * WPAD + kk + quad * 8];
            acc[nt] = __builtin_amdgcn_mfma_f32_16x16x32_f16(a, bf, acc[nt], 0, 0, 0);
        }
    }
    int rowC = blockIdx.x * 64 + wave * 16 + quad * 4;
    #pragma unroll
    for (int nt = 0; nt < 4; ++nt) {
        int col = nt * 16 + m;
        float bias = b[col];
        #pragma unroll
        for (int r = 0; r < 4; ++r) {
            int row = rowC + r;
            if (row < n)
                x_all[(size_t)row * (MAXL * HID) + col] = fmaxf(acc[nt][r] + bias, 0.f);
        }
    }
}

// ---------- per-node q/k/v grouped-linear transform (fp16-packed outputs) ----------
// out[d] = b[d] + sum_i x[g*8+i] * w[g*64 + i*8 + o], g=d>>3, o=d&7
// V is pre-scaled by dis[node]  (removes the dis[r] gather from the edge loop:
// nrm*out = dis_c * sum_l p_l * (dis_r * v_l))
__global__ void transform_kernel(const float* __restrict__ x_all,
                                 const float* __restrict__ wq, const float* __restrict__ bq,
                                 const float* __restrict__ wk, const float* __restrict__ bk,
                                 const float* __restrict__ wv, const float* __restrict__ bv,
                                 const float* __restrict__ dis,
                                 f16x2* __restrict__ Q2, f16x2* __restrict__ KV,
                                 int n, int L) {
    int t = blockIdx.x * blockDim.x + threadIdx.x;
    int node = t >> 5, u = t & 31;
    if (node >= n) return;
    int g = u >> 2;               // head/group of both dims
    int o0 = (u & 3) * 2;         // within-group output index of dim 2u
    const float* xrow = x_all + (size_t)node * (MAXL * HID);
    float d = dis[node];

    {   // Q from layer L-1
        const float* xg = xrow + (L - 1) * HID + g * 8;
        const float* wg = wq + g * 64;
        float a0 = bq[g * 8 + o0], a1 = bq[g * 8 + o0 + 1];
        #pragma unroll
        for (int i = 0; i < 8; ++i) {
            float xv = xg[i];
            a0 = fmaf(xv, wg[i * 8 + o0], a0);
            a1 = fmaf(xv, wg[i * 8 + o0 + 1], a1);
        }
        f16x2 q; q[0] = (f16)a0; q[1] = (f16)a1;
        Q2[(size_t)node * 32 + u] = q;
    }
    for (int ll = 0; ll < L; ++ll) {
        const float* xg = xrow + ll * HID + g * 8;
        const float* wgk = wk + g * 64;
        const float* wgv = wv + g * 64;
        float k0 = bk[g * 8 + o0], k1 = bk[g * 8 + o0 + 1];
        float v0 = bv[g * 8 + o0], v1 = bv[g * 8 + o0 + 1];
        #pragma unroll
        for (int i = 0; i < 8; ++i) {
            float xv = xg[i];
            k0 = fmaf(xv, wgk[i * 8 + o0], k0);
            k1 = fmaf(xv, wgk[i * 8 + o0 + 1], k1);
            v0 = fmaf(xv, wgv[i * 8 + o0], v0);
            v1 = fmaf(xv, wgv[i * 8 + o0 + 1], v1);
        }
        f16x2 kh; kh[0] = (f16)k0; kh[1] = (f16)k1;
        f16x2 vh; vh[0] = (f16)(v0 * d); vh[1] = (f16)(v1 * d);   // dis-scaled V
        size_t base = ((size_t)node * KVS + ll) * 2;
        KV[(base + 0) * 32 + u] = kh;
        KV[(base + 1) * 32 + u] = vh;
    }
}

// ---------- gather + attend: one wave64 per destination, 16 edges/iter ----------
// lane = slot*8 + head(u); each lane holds its head's full 8 dims (b128 fp16).
// Inner chain is csr_src -> KV only (dis folded into V); epilogue scales by dis_c.
template <int L>
__global__ void gather_kernel(const int* __restrict__ rowptr, const int* __restrict__ deg,
                              const int* __restrict__ csr_src, const float* __restrict__ dis,
                              const f16x8* __restrict__ Q8, const f16x8* __restrict__ KV8,
                              float* __restrict__ x_all, int n) {
    int wave = (int)((blockIdx.x * (size_t)blockDim.x + threadIdx.x) >> 6);
    int lane = threadIdx.x & 63;
    if (wave >= n) return;
    int c = wave;
    int u = lane & 7;         // head
    int slot = lane >> 3;     // edge slot
    F16x8 q; q.v = Q8[(size_t)c * 8 + u];
    float nc = dis[c];
    int beg = rowptr[c];
    int dc = deg[c] + 1;      // + self loop
    float acc[8];
    #pragma unroll
    for (int i = 0; i < 8; ++i) acc[i] = 0.f;

    for (int j = 0; j < dc; j += 16) {
        int jj0 = j + slot;
        int jj1 = j + slot + 8;
        bool va0 = jj0 < dc, va1 = jj1 < dc;
        int r0 = c, r1 = c;
        if (va0 && jj0 > 0) r0 = csr_src[beg + jj0 - 1];
        if (va1)            r1 = csr_src[beg + jj1 - 1];

        F16x8 kk0[L], vv0[L], kk1[L], vv1[L];
        size_t rb0 = (size_t)r0 * (KVS * 2 * 8);
        size_t rb1 = (size_t)r1 * (KVS * 2 * 8);
        #pragma unroll
        for (int ll = 0; ll < L; ++ll) {
            kk0[ll].v = KV8[rb0 + ll * 16 + u];
            vv0[ll].v = KV8[rb0 + ll * 16 + 8 + u];
            kk1[ll].v = KV8[rb1 + ll * 16 + u];
            vv1[ll].v = KV8[rb1 + ll * 16 + 8 + u];
        }
        float s0[L], s1[L];
        #pragma unroll
        for (int ll = 0; ll < L; ++ll) {
            float p0 = 0.f, p1 = 0.f;
            #pragma unroll
            for (int i2 = 0; i2 < 4; ++i2) {
                p0 = dot2(q.h[i2], kk0[ll].h[i2], p0);
                p1 = dot2(q.h[i2], kk1[ll].h[i2], p1);
            }
            s0[ll] = p0 * 0.35355339059327373f;   // 1/sqrt(8)
            s1[ll] = p1 * 0.35355339059327373f;
        }
        float m0 = s0[0], m1 = s1[0];
        #pragma unroll
        for (int ll = 1; ll < L; ++ll) { m0 = fmaxf(m0, s0[ll]); m1 = fmaxf(m1, s1[ll]); }
        float sum0 = 0.f, sum1 = 0.f;
        #pragma unroll
        for (int ll = 0; ll < L; ++ll) {
            s0[ll] = __expf(s0[ll] - m0); sum0 += s0[ll];
            s1[ll] = __expf(s1[ll] - m1); sum1 += s1[ll];
        }
        float inv0 = va0 ? 1.f / sum0 : 0.f;      // V already dis_r-scaled
        float inv1 = va1 ? 1.f / sum1 : 0.f;

        __half2 ha[4];
        #pragma unroll
        for (int i2 = 0; i2 < 4; ++i2) ha[i2] = __float2half2_rn(0.f);
        #pragma unroll
        for (int ll = 0; ll < L; ++ll) {
            __half2 p0 = __float2half2_rn(s0[ll] * inv0);
            __half2 p1 = __float2half2_rn(s1[ll] * inv1);
            #pragma unroll
            for (int i2 = 0; i2 < 4; ++i2) {
                ha[i2] = __hfma2(p0, vv0[ll].hh[i2], ha[i2]);
                ha[i2] = __hfma2(p1, vv1[ll].hh[i2], ha[i2]);
            }
        }
        #pragma unroll
        for (int i2 = 0; i2 < 4; ++i2) {
            float2 f = __half22float2(ha[i2]);
            acc[i2 * 2]     += f.x;
            acc[i2 * 2 + 1] += f.y;
        }
    }
    // reduce the 8 edge slots (once per node)
    #pragma unroll
    for (int off = 8; off < 64; off <<= 1) {
        #pragma unroll
        for (int i = 0; i < 8; ++i) acc[i] += __shfl_xor(acc[i], off);
    }
    if (slot == 0) {
        float4* dst = (float4*)(x_all + ((size_t)c * MAXL + L) * HID + u * 8);
        dst[0] = make_float4(fmaxf(acc[0] * nc, 0.f), fmaxf(acc[1] * nc, 0.f),
                             fmaxf(acc[2] * nc, 0.f), fmaxf(acc[3] * nc, 0.f));
        dst[1] = make_float4(fmaxf(acc[4] * nc, 0.f), fmaxf(acc[5] * nc, 0.f),
                             fmaxf(acc[6] * nc, 0.f), fmaxf(acc[7] * nc, 0.f));
    }
}

// ---------- final: logits = x_all[:,3] @ W2 + b2; log_softmax over 32 classes ----------
__global__ void final_kernel(const float* __restrict__ x_all, const float* __restrict__ w2,
                             const float* __restrict__ b2, float* __restrict__ out, int n) {
    int t = blockIdx.x * blockDim.x + threadIdx.x;
    int node = t >> 5;
    int o = t & 31;
    if (node >= n) return;
    const float* xr = x_all + (size_t)node * (MAXL * HID) + 3 * HID;
    float logit = b2[o];
    #pragma unroll
    for (int d = 0; d < HID; ++d) logit = fmaf(xr[d], w2[d * N_CLASS + o], logit);
    float m = logit;
    for (int off = 16; off; off >>= 1) m = fmaxf(m, __shfl_xor(m, off, 32));
    float e = expf(logit - m);
    float sum = e;
    for (int off = 16; off; off >>= 1) sum += __shfl_xor(sum, off, 32);
    out[(size_t)node * N_CLASS + o] = (logit - m) - logf(sum);
}

extern "C" void kernel_launch(void* const* d_in, const int* in_sizes, int n_in,
                              void* d_out, int out_size, void* d_ws, size_t ws_size,
                              hipStream_t stream) {
    const float* x      = (const float*)d_in[0];
    const int*   eidx   = (const int*)d_in[1];     // (2, E)
    const float* lin1_w = (const float*)d_in[2];
    const float* lin1_b = (const float*)d_in[3];
    const float* wq     = (const float*)d_in[4];   // (3, 8, 8, 8)
    const float* bq     = (const float*)d_in[5];   // (3, 64)
    const float* wk     = (const float*)d_in[6];
    const float* bk     = (const float*)d_in[7];
    const float* wv     = (const float*)d_in[8];
    const float* bv     = (const float*)d_in[9];
    const float* lin2_w = (const float*)d_in[10];  // (64, 32)
    const float* lin2_b = (const float*)d_in[11];
    float* out = (float*)d_out;

    const int n  = NN;
    const int E  = NE;
    const int* row = eidx;
    const int* col = eidx + E;

    // workspace layout (16B-aligned where vector-accessed)
    char* ws = (char*)d_ws;
    float*  x_all  = (float*)ws;   ws += (size_t)NN * MAXL * HID * 4;        // 25.6 MB
    f16x2*  Q2     = (f16x2*)ws;   ws += (size_t)NN * 32 * 4;                // 3.2 MB
    f16x2*  KV     = (f16x2*)ws;   ws += (size_t)NN * KVS * 2 * 32 * 4;      // 19.2 MB
    float*  dis    = (float*)ws;   ws += (size_t)NN * 4;
    int*    deg    = (int*)ws;     ws += (size_t)NN * 4;
    int*    rowptr = (int*)ws;     ws += (size_t)NN * 4;
    int*    cursor = (int*)ws;     ws += (size_t)NN * 4;
    int*    csr    = (int*)ws;     ws += (size_t)NE * 4;                     // 1.6 MB
    f16*    wt16   = (f16*)ws;     ws += (size_t)HID * F_IN * 2;             // 32 KB
    int*    bsum   = (int*)ws;     ws += 128 * 4;

    // 1. degree + norm + CSR build (+ W1 fp16 transpose)
    hipMemsetAsync(deg, 0, (size_t)NN * 4, stream);
    deg_kernel<<<(E + 255) / 256, 256, 0, stream>>>(col, deg, E);
    scanA_kernel<<<SCAN_NB, 256, 0, stream>>>(deg, bsum, n);
    scanB_kernel<<<1, 128, 0, stream>>>(bsum, SCAN_NB);
    scanC_kernel<<<SCAN_NB, 256, 0, stream>>>(deg, bsum, rowptr, cursor, dis, n);
    scatter_kernel<<<(E + 255) / 256, 256, 0, stream>>>(row, col, cursor, csr, E);
    wprep_kernel<<<(HID * F_IN + 255) / 256, 256, 0, stream>>>(lin1_w, wt16);

    // 2. lin1 (MFMA) -> x_all layer 0
    lin1_mfma_kernel<<<(n + 63) / 64, 256, 0, stream>>>(x, (const f16x8*)wt16, lin1_b, x_all, n);

    // 3. three DNA conv layers
    for (int l = 0; l < 3; ++l) {
        int L = l + 1;
        transform_kernel<<<(n * 32 + 255) / 256, 256, 0, stream>>>(
            x_all, wq + l * 512, bq + l * 64, wk + l * 512, bk + l * 64,
            wv + l * 512, bv + l * 64, dis, Q2, KV, n, L);
        int blocks = (n + 3) / 4;   // 4 nodes (waves) per 256-thread block
        if (L == 1)      gather_kernel<1><<<blocks, 256, 0, stream>>>(rowptr, deg, csr, dis, (const f16x8*)Q2, (const f16x8*)KV, x_all, n);
        else if (L == 2) gather_kernel<2><<<blocks, 256, 0, stream>>>(rowptr, deg, csr, dis, (const f16x8*)Q2, (const f16x8*)KV, x_all, n);
        else             gather_kernel<3><<<blocks, 256, 0, stream>>>(rowptr, deg, csr, dis, (const f16x8*)Q2, (const f16x8*)KV, x_all, n);
    }

    // 4. classifier + log_softmax
    final_kernel<<<(n * N_CLASS + 255) / 256, 256, 0, stream>>>(x_all, lin2_w, lin2_b, out, n);
}